// Round 10
// baseline (289.480 us; speedup 1.0000x reference)
//
#include <hip/hip_runtime.h>
#include <hip/hip_bf16.h>
#include <math.h>

#define H    128
#define NC   5
#define LPI  264   // internal A row stride (ushorts): 256 + 8 pad
#define LPL  136   // leaf A row stride: 128 + 8 pad
#define HPAD 136   // head h row stride
#define CBP  132   // child-c LDS row stride (floats): 128 + 4 (breaks 4-way bank alias)

typedef unsigned short ushort_t;
using frag_ab = __attribute__((ext_vector_type(8))) short;   // 8 bf16 (4 VGPRs)
using frag_cd = __attribute__((ext_vector_type(4))) float;   // 4 fp32 acc

__device__ __forceinline__ float fsig(float x) { return 1.0f / (1.0f + __expf(-x)); }
__device__ __forceinline__ float ftanh_(float x) {
    float e = __expf(-2.0f * fabsf(x));
    float t = (1.0f - e) / (1.0f + e);
    return copysignf(t, x);
}
__device__ __forceinline__ ushort_t f2bf(float f) {
    __hip_bfloat16 b = __float2bfloat16(f);
    return *reinterpret_cast<ushort_t*>(&b);
}

// ---------------------------------------------------------------------------
// Prep: B-fragment-native bf16 layouts.
//   Wf   [kcq][512 cols][8]  cols = [Ui|Uo|Uu|F], F panel: k<128 -> F1, k>=128 -> F2
//   Wlf  [kcq][384 cols][8]  cols = [Wi|Wo|Wu], K=128
//   Woutf[kcq][16  cols][8]  cols 0..4 = classes, rest 0, K=128
// ---------------------------------------------------------------------------
__global__ __launch_bounds__(256) void prep_weights(
    const float* __restrict__ Ui, const float* __restrict__ Uo, const float* __restrict__ Uu,
    const float* __restrict__ F1, const float* __restrict__ F2,
    const float* __restrict__ Wi, const float* __restrict__ Wo, const float* __restrict__ Wu,
    const float* __restrict__ Wout,
    ushort_t* __restrict__ Wf, ushort_t* __restrict__ Wlf, ushort_t* __restrict__ Woutf)
{
    int e = blockIdx.x * 256 + threadIdx.x;   // 712*256 = 182272 = 131072+49152+2048
    if (e < 131072) {
        int kc = e >> 12, rem = e & 4095;     // 512 cols * 8 = 4096 per kcq
        int n = rem >> 3, j7 = rem & 7;
        int k = kc * 8 + j7;
        int g = n >> 7, jc = n & 127;
        float v;
        if (g == 0)      v = Ui[jc * 256 + k];
        else if (g == 1) v = Uo[jc * 256 + k];
        else if (g == 2) v = Uu[jc * 256 + k];
        else             v = (k < 128) ? F1[jc * 128 + k] : F2[jc * 128 + k - 128];
        Wf[e] = f2bf(v);
    } else if (e < 180224) {
        int e2 = e - 131072;
        int kc = e2 / 3072, rem = e2 % 3072;
        int n = rem >> 3, j7 = rem & 7;
        int k = kc * 8 + j7;
        int g = n >> 7, jc = n & 127;
        float v = (g == 0) ? Wi[jc * 128 + k] : (g == 1) ? Wo[jc * 128 + k] : Wu[jc * 128 + k];
        Wlf[e2] = f2bf(v);
    } else {
        int e3 = e - 180224;               // 0..2047
        int kcq = e3 >> 7, rem = e3 & 127;
        int col = rem >> 3, j7 = rem & 7;
        int k = kcq * 8 + j7;
        float v = (col < NC) ? Wout[col * H + k] : 0.0f;
        Woutf[e3] = f2bf(v);
    }
}

// ---------------------------------------------------------------------------
// Fused leaf..l3: 32 leaves -> 16 l1 -> 8 l2 -> 4 l3 per block (the whole
// 4-level subtree is block-local). l1/l2 h/c live only in LDS; only l3 h/c
// goes to global (was: l1 h/c = 12.6 MB round-trip). 512 thr / 8 waves,
// one jt per wave (3x-proven). xs3/xs4 sized 16 rows so the head/A-frag
// reads of garbage rows stay in-bounds (values masked at store).
// ---------------------------------------------------------------------------
__global__ __launch_bounds__(512) void leaf_l3_mfma(
    const int* __restrict__ tokens, const float* __restrict__ embed,
    const ushort_t* __restrict__ Wlf, const ushort_t* __restrict__ Wf,
    const ushort_t* __restrict__ Woutf,
    const float* __restrict__ bi, const float* __restrict__ bo, const float* __restrict__ bu,
    const float* __restrict__ bui, const float* __restrict__ buo, const float* __restrict__ buu,
    const float* __restrict__ bf1, const float* __restrict__ bf2,
    const float* __restrict__ bout,
    const int* __restrict__ labels, float* __restrict__ lab_out,
    ushort_t* __restrict__ h3_out, float* __restrict__ c3_out,
    float* __restrict__ out)
{
    __shared__ ushort_t xs [32 * LPL];    // leaf A rows (bf16 embed)
    __shared__ ushort_t hh [32 * HPAD];   // head rows (leaf, l1, l2, l3)
    __shared__ float    cbL[32 * CBP];    // leaf c
    __shared__ ushort_t xs2[16 * LPI];    // l1 A rows = [h_left | h_right]
    __shared__ float    cb1[16 * CBP];    // l1 c
    __shared__ ushort_t xs3[16 * LPI];    // l2 A rows (8 valid, 16 for OOB safety)
    __shared__ float    cb2[8  * CBP];    // l2 c
    __shared__ ushort_t xs4[16 * LPI];    // l3 A rows (4 valid)
    const int tid = threadIdx.x;
    const int nb  = blockIdx.x;

    // fused labels: 2048 blocks * 64 = 131072 >= 131071
    if (tid < 64) {
        int id = nb * 64 + tid;
        if (id < 131071) lab_out[id] = (float)labels[id];
    }

    // stage leaf A: node m = tid>>4, 8 floats at kp=(tid&15)*8, fp32 -> bf16
    {
        int m = tid >> 4, kp = (tid & 15) * 8;
        const float* src = embed + (size_t)tokens[nb * 32 + m] * H + kp;
        ushort_t tmp[8];
#pragma unroll
        for (int v = 0; v < 2; ++v) {
            float4 f = *(const float4*)(src + v * 4);
            tmp[v * 4 + 0] = f2bf(f.x); tmp[v * 4 + 1] = f2bf(f.y);
            tmp[v * 4 + 2] = f2bf(f.z); tmp[v * 4 + 3] = f2bf(f.w);
        }
        *(uint4*)&xs[m * LPL + kp] = *(uint4*)tmp;
    }

    const int w = tid >> 6, lane = tid & 63;
    const int mA = lane & 15, q = lane >> 4, nlane = lane & 15;

    frag_ab wb[4];
#pragma unroll
    for (int kc8 = 0; kc8 < 4; ++kc8)
        wb[kc8] = *(const frag_ab*)&Woutf[(((kc8 * 4 + q) * 16) + nlane) * 8];
    float bout_l = (nlane < NC) ? bout[nlane] : 0.0f;

    const int jt = w;                      // one j-tile per wave
    const int j = jt * 16 + nlane;
    const float bui_ = bui[j], buo_ = buo[j], buu_ = buu[j];
    const float bf1_ = bf1[j], bf2_ = bf2[j];
    __syncthreads();                       // xs ready

    // ---- leaf LSTM (K=128, gates i,o,u) ----
    frag_ab a[2][4];
#pragma unroll
    for (int t = 0; t < 2; ++t)
#pragma unroll
        for (int kc8 = 0; kc8 < 4; ++kc8)
            a[t][kc8] = *(const frag_ab*)&xs[(t * 16 + mA) * LPL + (kc8 * 4 + q) * 8];

    {
        frag_cd acc[3][2];
#pragma unroll
        for (int g = 0; g < 3; ++g)
#pragma unroll
            for (int t = 0; t < 2; ++t) acc[g][t] = (frag_cd){0.f, 0.f, 0.f, 0.f};
#pragma unroll
        for (int kc8 = 0; kc8 < 4; ++kc8) {
            int kcq = kc8 * 4 + q;
            const ushort_t* wp = &Wlf[((size_t)kcq * 384 + jt * 16 + nlane) * 8];
#pragma unroll
            for (int g = 0; g < 3; ++g) {
                frag_ab b = *(const frag_ab*)(wp + (size_t)g * H * 8);
                acc[g][0] = __builtin_amdgcn_mfma_f32_16x16x32_bf16(a[0][kc8], b, acc[g][0], 0, 0, 0);
                acc[g][1] = __builtin_amdgcn_mfma_f32_16x16x32_bf16(a[1][kc8], b, acc[g][1], 0, 0, 0);
            }
        }
        float bi_ = bi[j], bo_ = bo[j], bu_ = bu[j];
#pragma unroll
        for (int t = 0; t < 2; ++t)
#pragma unroll
            for (int r = 0; r < 4; ++r) {
                int nloc = t * 16 + q * 4 + r;
                float i_ = fsig(acc[0][t][r] + bi_);
                float o_ = fsig(acc[1][t][r] + bo_);
                float u_ = ftanh_(acc[2][t][r] + bu_);
                float c_ = i_ * u_;
                float h_ = o_ * ftanh_(c_);
                cbL[nloc * CBP + j] = c_;
                ushort_t hb = f2bf(h_);
                hh[nloc * HPAD + j] = hb;
                xs2[(nloc >> 1) * LPI + (nloc & 1) * H + j] = hb;
            }
    }
    __syncthreads();                       // leaf hh/cbL/xs2 ready

    // ---- leaf head (waves 0,1) + l1 A-fragment loads ----
    frag_ab a1[8];
#pragma unroll
    for (int kc8 = 0; kc8 < 8; ++kc8)
        a1[kc8] = *(const frag_ab*)&xs2[mA * LPI + (kc8 * 4 + q) * 8];

    if (w < 2) {
        frag_cd ha = (frag_cd){0.f, 0.f, 0.f, 0.f};
#pragma unroll
        for (int kc8 = 0; kc8 < 4; ++kc8) {
            frag_ab av = *(const frag_ab*)&hh[(w * 16 + mA) * HPAD + (kc8 * 4 + q) * 8];
            ha = __builtin_amdgcn_mfma_f32_16x16x32_bf16(av, wb[kc8], ha, 0, 0, 0);
        }
        if (nlane < NC) {
#pragma unroll
            for (int r = 0; r < 4; ++r)
                out[(size_t)(nb * 32 + w * 16 + q * 4 + r) * NC + nlane] = ha[r] + bout_l;
        }
    }
    __syncthreads();                       // leaf head done; hh reusable

    // ---- l1 LSTM (16 nodes; c/h -> LDS only) ----
    {
        frag_cd acc[5];
#pragma unroll
        for (int g = 0; g < 5; ++g) acc[g] = (frag_cd){0.f, 0.f, 0.f, 0.f};
#pragma unroll
        for (int kc8 = 0; kc8 < 8; ++kc8) {
            int kcq = kc8 * 4 + q;
            const ushort_t* wp = &Wf[((size_t)kcq * 512 + jt * 16 + nlane) * 8];
#pragma unroll
            for (int g = 0; g < 4; ++g) {
                frag_ab b = *(const frag_ab*)(wp + (size_t)g * H * 8);
                int gi = (g < 3) ? g : (kc8 < 4 ? 3 : 4);
                acc[gi] = __builtin_amdgcn_mfma_f32_16x16x32_bf16(a1[kc8], b, acc[gi], 0, 0, 0);
            }
        }
#pragma unroll
        for (int r = 0; r < 4; ++r) {
            int nloc = q * 4 + r;
            float i_  = fsig(acc[0][r] + bui_);
            float o_  = fsig(acc[1][r] + buo_);
            float u_  = ftanh_(acc[2][r] + buu_);
            float f1_ = fsig(acc[3][r] + bf1_);
            float f2_ = fsig(acc[4][r] + bf2_);
            float cl = cbL[(2 * nloc) * CBP + j];
            float cr = cbL[(2 * nloc + 1) * CBP + j];
            float c_ = fmaf(i_, u_, fmaf(f1_, cl, f2_ * cr));
            float h_ = o_ * ftanh_(c_);
            cb1[nloc * CBP + j] = c_;
            ushort_t hb = f2bf(h_);
            hh[nloc * HPAD + j] = hb;
            xs3[(nloc >> 1) * LPI + (nloc & 1) * H + j] = hb;
        }
    }
    __syncthreads();                       // l1 hh/cb1/xs3 ready

    // ---- l1 head (wave 0) + l2 A-fragment loads ----
    frag_ab a2[8];
#pragma unroll
    for (int kc8 = 0; kc8 < 8; ++kc8)
        a2[kc8] = *(const frag_ab*)&xs3[mA * LPI + (kc8 * 4 + q) * 8];

    if (w == 0) {
        frag_cd ha = (frag_cd){0.f, 0.f, 0.f, 0.f};
#pragma unroll
        for (int kc8 = 0; kc8 < 4; ++kc8) {
            frag_ab av = *(const frag_ab*)&hh[mA * HPAD + (kc8 * 4 + q) * 8];
            ha = __builtin_amdgcn_mfma_f32_16x16x32_bf16(av, wb[kc8], ha, 0, 0, 0);
        }
        if (nlane < NC) {
#pragma unroll
            for (int r = 0; r < 4; ++r)
                out[(size_t)65536 * NC + (size_t)(nb * 16 + q * 4 + r) * NC + nlane] = ha[r] + bout_l;
        }
    }
    __syncthreads();                       // l1 head done; hh reusable

    // ---- l2 LSTM (8 nodes) ----
    {
        frag_cd acc[5];
#pragma unroll
        for (int g = 0; g < 5; ++g) acc[g] = (frag_cd){0.f, 0.f, 0.f, 0.f};
#pragma unroll
        for (int kc8 = 0; kc8 < 8; ++kc8) {
            int kcq = kc8 * 4 + q;
            const ushort_t* wp = &Wf[((size_t)kcq * 512 + jt * 16 + nlane) * 8];
#pragma unroll
            for (int g = 0; g < 4; ++g) {
                frag_ab b = *(const frag_ab*)(wp + (size_t)g * H * 8);
                int gi = (g < 3) ? g : (kc8 < 4 ? 3 : 4);
                acc[gi] = __builtin_amdgcn_mfma_f32_16x16x32_bf16(a2[kc8], b, acc[gi], 0, 0, 0);
            }
        }
#pragma unroll
        for (int r = 0; r < 4; ++r) {
            int nloc = q * 4 + r;
            if (nloc < 8) {
                float i_  = fsig(acc[0][r] + bui_);
                float o_  = fsig(acc[1][r] + buo_);
                float u_  = ftanh_(acc[2][r] + buu_);
                float f1_ = fsig(acc[3][r] + bf1_);
                float f2_ = fsig(acc[4][r] + bf2_);
                float cl = cb1[(2 * nloc) * CBP + j];
                float cr = cb1[(2 * nloc + 1) * CBP + j];
                float c_ = fmaf(i_, u_, fmaf(f1_, cl, f2_ * cr));
                float h_ = o_ * ftanh_(c_);
                cb2[nloc * CBP + j] = c_;
                ushort_t hb = f2bf(h_);
                hh[nloc * HPAD + j] = hb;
                xs4[(nloc >> 1) * LPI + (nloc & 1) * H + j] = hb;
            }
        }
    }
    __syncthreads();                       // l2 hh/cb2/xs4 ready

    // ---- l2 head (wave 0) + l3 A-fragment loads ----
    frag_ab a3[8];
#pragma unroll
    for (int kc8 = 0; kc8 < 8; ++kc8)
        a3[kc8] = *(const frag_ab*)&xs4[mA * LPI + (kc8 * 4 + q) * 8];

    if (w == 0) {
        frag_cd ha = (frag_cd){0.f, 0.f, 0.f, 0.f};
#pragma unroll
        for (int kc8 = 0; kc8 < 4; ++kc8) {
            frag_ab av = *(const frag_ab*)&hh[mA * HPAD + (kc8 * 4 + q) * 8];
            ha = __builtin_amdgcn_mfma_f32_16x16x32_bf16(av, wb[kc8], ha, 0, 0, 0);
        }
        if (nlane < NC) {
#pragma unroll
            for (int r = 0; r < 4; ++r) {
                int nd = q * 4 + r;
                if (nd < 8)
                    out[(size_t)98304 * NC + (size_t)(nb * 8 + nd) * NC + nlane] = ha[r] + bout_l;
            }
        }
    }
    __syncthreads();                       // l2 head done; hh reusable

    // ---- l3 LSTM (4 nodes; h/c -> GLOBAL for the l4 dispatch) ----
    {
        frag_cd acc[5];
#pragma unroll
        for (int g = 0; g < 5; ++g) acc[g] = (frag_cd){0.f, 0.f, 0.f, 0.f};
#pragma unroll
        for (int kc8 = 0; kc8 < 8; ++kc8) {
            int kcq = kc8 * 4 + q;
            const ushort_t* wp = &Wf[((size_t)kcq * 512 + jt * 16 + nlane) * 8];
#pragma unroll
            for (int g = 0; g < 4; ++g) {
                frag_ab b = *(const frag_ab*)(wp + (size_t)g * H * 8);
                int gi = (g < 3) ? g : (kc8 < 4 ? 3 : 4);
                acc[gi] = __builtin_amdgcn_mfma_f32_16x16x32_bf16(a3[kc8], b, acc[gi], 0, 0, 0);
            }
        }
#pragma unroll
        for (int r = 0; r < 4; ++r) {
            int nloc = q * 4 + r;
            if (nloc < 4) {
                float i_  = fsig(acc[0][r] + bui_);
                float o_  = fsig(acc[1][r] + buo_);
                float u_  = ftanh_(acc[2][r] + buu_);
                float f1_ = fsig(acc[3][r] + bf1_);
                float f2_ = fsig(acc[4][r] + bf2_);
                float cl = cb2[(2 * nloc) * CBP + j];
                float cr = cb2[(2 * nloc + 1) * CBP + j];
                float c_ = fmaf(i_, u_, fmaf(f1_, cl, f2_ * cr));
                float h_ = o_ * ftanh_(c_);
                c3_out[(size_t)(nb * 4 + nloc) * H + j] = c_;
                ushort_t hb = f2bf(h_);
                h3_out[(size_t)(nb * 4 + nloc) * H + j] = hb;
                hh[nloc * HPAD + j] = hb;
            }
        }
    }
    __syncthreads();                       // l3 hh ready

    if (w == 0) {                          // l3 head
        frag_cd ha = (frag_cd){0.f, 0.f, 0.f, 0.f};
#pragma unroll
        for (int kc8 = 0; kc8 < 4; ++kc8) {
            frag_ab av = *(const frag_ab*)&hh[mA * HPAD + (kc8 * 4 + q) * 8];
            ha = __builtin_amdgcn_mfma_f32_16x16x32_bf16(av, wb[kc8], ha, 0, 0, 0);
        }
        if (nlane < NC) {
#pragma unroll
            for (int r = 0; r < 4; ++r) {
                int nd = q * 4 + r;
                if (nd < 4)
                    out[(size_t)114688 * NC + (size_t)(nb * 4 + nd) * NC + nlane] = ha[r] + bout_l;
            }
        }
    }
}

// ---------------------------------------------------------------------------
// Subtree kernel: FOUR levels per block (32 -> 16 -> 8 -> 4 nodes). Only the
// LAST level's h/c goes to global. 512 thr / 8 waves, one jt per wave.
// #pragma unroll 1 on the lev loop: spill insurance (R1/R2 lesson).
// ---------------------------------------------------------------------------
__global__ __launch_bounds__(512) void subtree_mfma(
    const ushort_t* __restrict__ h_prev, const float* __restrict__ c_prev,
    const ushort_t* __restrict__ Wf, const ushort_t* __restrict__ Woutf,
    const float* __restrict__ bui, const float* __restrict__ buo, const float* __restrict__ buu,
    const float* __restrict__ bf1, const float* __restrict__ bf2,
    const float* __restrict__ bout,
    ushort_t* __restrict__ h_out, float* __restrict__ c_out,
    float* __restrict__ out_base)
{
    __shared__ ushort_t xsA[32 * LPI];   // A rows, even levels
    __shared__ ushort_t xsB[16 * LPI];   // A rows, odd levels
    __shared__ float    cbA[32 * CBP];   // c, even-level outputs
    __shared__ float    cbB[16 * CBP];   // c, odd-level outputs
    __shared__ ushort_t hh [32 * HPAD];
    const int tid = threadIdx.x;
    const int NB  = gridDim.x;

    {   // stage level-0 A: 32 rows x 256 from h_prev (64 children x 128)
        int m = tid >> 4, kp = (tid & 15) * 16;
        const uint4* s = (const uint4*)(h_prev +
            ((size_t)2 * (blockIdx.x * 32 + m) + (kp >> 7)) * H + (kp & 127));
        uint4* d = (uint4*)&xsA[m * LPI + kp];
        d[0] = s[0]; d[1] = s[1];
    }

    const int w = tid >> 6, lane = tid & 63;
    const int mA = lane & 15, q = lane >> 4, nlane = lane & 15;

    frag_ab wb[4];
#pragma unroll
    for (int kc8 = 0; kc8 < 4; ++kc8)
        wb[kc8] = *(const frag_ab*)&Woutf[(((kc8 * 4 + q) * 16) + nlane) * 8];
    float bout_l = (nlane < NC) ? bout[nlane] : 0.0f;

    const int jt = w;                    // one j-tile per wave
    const int j = jt * 16 + nlane;
    const float bi_ = bui[j], bo_ = buo[j], bu_ = buu[j], b1_ = bf1[j], b2_ = bf2[j];

    size_t out_off = 0;
#pragma unroll 1
    for (int lev = 0; lev < 4; ++lev) {
        const int N = 32 >> lev;                       // nodes/block this level
        const int ntiles = (N + 15) >> 4;              // 2,1,1,1
        const int gbase = blockIdx.x * N;              // global node base
        ushort_t* xs_cur = (lev & 1) ? xsB : xsA;
        ushort_t* xs_nxt = (lev & 1) ? xsA : xsB;
        float*    cb_out = (lev & 1) ? cbB : cbA;
        const float* cb_in = (lev & 1) ? cbA : cbB;
        __syncthreads();   // A/c ready; previous head done

        for (int t = 0; t < ntiles; ++t) {
            frag_cd acc[5];
#pragma unroll
            for (int g = 0; g < 5; ++g) acc[g] = (frag_cd){0.f, 0.f, 0.f, 0.f};
#pragma unroll
            for (int kc8 = 0; kc8 < 8; ++kc8) {
                int kcq = kc8 * 4 + q;
                frag_ab av = *(const frag_ab*)&xs_cur[(t * 16 + mA) * LPI + kcq * 8];
                const ushort_t* wp = &Wf[((size_t)kcq * 512 + jt * 16 + nlane) * 8];
#pragma unroll
                for (int g = 0; g < 4; ++g) {
                    frag_ab b = *(const frag_ab*)(wp + (size_t)g * H * 8);
                    int gi = (g < 3) ? g : (kc8 < 4 ? 3 : 4);   // constant after unroll
                    acc[gi] = __builtin_amdgcn_mfma_f32_16x16x32_bf16(av, b, acc[gi], 0, 0, 0);
                }
            }
#pragma unroll
            for (int r = 0; r < 4; ++r) {
                int nloc = t * 16 + q * 4 + r;
                if (nloc < N) {
                    float i_  = fsig(acc[0][r] + bi_);
                    float o_  = fsig(acc[1][r] + bo_);
                    float u_  = ftanh_(acc[2][r] + bu_);
                    float f1_ = fsig(acc[3][r] + b1_);
                    float f2_ = fsig(acc[4][r] + b2_);
                    float cl, cr;
                    if (lev == 0) {
                        cl = c_prev[((size_t)2 * (gbase + nloc)) * H + j];
                        cr = c_prev[((size_t)2 * (gbase + nloc) + 1) * H + j];
                    } else {
                        cl = cb_in[(2 * nloc) * CBP + j];
                        cr = cb_in[(2 * nloc + 1) * CBP + j];
                    }
                    float c_ = fmaf(i_, u_, fmaf(f1_, cl, f2_ * cr));
                    float h_ = o_ * ftanh_(c_);
                    ushort_t hb = f2bf(h_);
                    hh[nloc * HPAD + j] = hb;
                    if (lev < 3) {
                        cb_out[nloc * CBP + j] = c_;
                        xs_nxt[(nloc >> 1) * LPI + (nloc & 1) * H + j] = hb;
                    } else {            // last level: h/c to global for next dispatch
                        c_out[(size_t)(gbase + nloc) * H + j] = c_;
                        h_out[(size_t)(gbase + nloc) * H + j] = hb;
                    }
                }
            }
        }
        __syncthreads();   // hh ready
        if (w < ntiles) {
            frag_cd ha = (frag_cd){0.f, 0.f, 0.f, 0.f};
#pragma unroll
            for (int kc8 = 0; kc8 < 4; ++kc8) {
                frag_ab av = *(const frag_ab*)&hh[(w * 16 + mA) * HPAD + (kc8 * 4 + q) * 8];
                ha = __builtin_amdgcn_mfma_f32_16x16x32_bf16(av, wb[kc8], ha, 0, 0, 0);
            }
            if (nlane < NC) {
#pragma unroll
                for (int r = 0; r < 4; ++r) {
                    int nd = w * 16 + q * 4 + r;
                    if (nd < N)
                        out_base[out_off + (size_t)(gbase + nd) * NC + nlane] = ha[r] + bout_l;
                }
            }
        }
        out_off += (size_t)NB * N * NC;
    }
}

// ---------------------------------------------------------------------------
// Tail: levels N=16,8,4,2,1 in ONE block of 512 threads (8 waves).
// ---------------------------------------------------------------------------
__global__ __launch_bounds__(512) void tail_mfma(
    const ushort_t* __restrict__ h_prev, const float* __restrict__ c_prev,
    const ushort_t* __restrict__ Wf, const ushort_t* __restrict__ Woutf,
    const float* __restrict__ bui, const float* __restrict__ buo, const float* __restrict__ buu,
    const float* __restrict__ bf1, const float* __restrict__ bf2,
    const float* __restrict__ bout, float* __restrict__ out)
{
    __shared__ ushort_t xsA[16 * LPI];   // A rows, even levels
    __shared__ ushort_t xsB[16 * LPI];   // A rows, odd levels (8 valid, 16 for OOB safety)
    __shared__ float    cbA[16 * H];
    __shared__ float    cbB[8 * H];
    __shared__ ushort_t hh[16 * HPAD];
    const int tid = threadIdx.x;
    const int w = tid >> 6, lane = tid & 63;
    const int mA = lane & 15, q = lane >> 4, nlane = lane & 15;

    {   // stage level-0 A: 16 rows x 256 from h_prev (32 children x 128)
        int m = tid >> 5, kp = (tid & 31) * 8;
        const uint4* s = (const uint4*)(h_prev + ((size_t)2 * m + (kp >> 7)) * H + (kp & 127));
        *(uint4*)&xsA[m * LPI + kp] = s[0];
    }

    frag_ab wb[4];
#pragma unroll
    for (int kc8 = 0; kc8 < 4; ++kc8)
        wb[kc8] = *(const frag_ab*)&Woutf[(((kc8 * 4 + q) * 16) + nlane) * 8];
    float bout_l = (nlane < NC) ? bout[nlane] : 0.0f;

    const int jt = w;                    // one j-tile per wave
    const int j = jt * 16 + nlane;
    const float bi_ = bui[j], bo_ = buo[j], bu_ = buu[j], b1_ = bf1[j], b2_ = bf2[j];

    float* outp = out;
#pragma unroll 1
    for (int lev = 0; lev < 5; ++lev) {
        const int N = 16 >> lev;
        ushort_t* xs_cur = (lev & 1) ? xsB : xsA;
        ushort_t* xs_nxt = (lev & 1) ? xsA : xsB;
        float*    cb_out = (lev & 1) ? cbB : cbA;
        const float* cb_in = (lev & 1) ? cbA : cbB;
        __syncthreads();   // A/c ready; previous head done

        {
            frag_cd acc[5];
#pragma unroll
            for (int g = 0; g < 5; ++g) acc[g] = (frag_cd){0.f, 0.f, 0.f, 0.f};
#pragma unroll
            for (int kc8 = 0; kc8 < 8; ++kc8) {
                int kcq = kc8 * 4 + q;
                frag_ab av = *(const frag_ab*)&xs_cur[mA * LPI + kcq * 8];
                const ushort_t* wp = &Wf[((size_t)kcq * 512 + jt * 16 + nlane) * 8];
#pragma unroll
                for (int g = 0; g < 4; ++g) {
                    frag_ab b = *(const frag_ab*)(wp + (size_t)g * H * 8);
                    int gi = (g < 3) ? g : (kc8 < 4 ? 3 : 4);   // constant after unroll
                    acc[gi] = __builtin_amdgcn_mfma_f32_16x16x32_bf16(av, b, acc[gi], 0, 0, 0);
                }
            }
#pragma unroll
            for (int r = 0; r < 4; ++r) {
                int nloc = q * 4 + r;
                if (nloc < N) {
                    float i_  = fsig(acc[0][r] + bi_);
                    float o_  = fsig(acc[1][r] + bo_);
                    float u_  = ftanh_(acc[2][r] + bu_);
                    float f1_ = fsig(acc[3][r] + b1_);
                    float f2_ = fsig(acc[4][r] + b2_);
                    float cl, cr;
                    if (lev == 0) {
                        cl = c_prev[((size_t)2 * nloc) * H + j];
                        cr = c_prev[((size_t)2 * nloc + 1) * H + j];
                    } else {
                        cl = cb_in[(2 * nloc) * H + j];
                        cr = cb_in[(2 * nloc + 1) * H + j];
                    }
                    float c_ = fmaf(i_, u_, fmaf(f1_, cl, f2_ * cr));
                    float h_ = o_ * ftanh_(c_);
                    cb_out[nloc * H + j] = c_;
                    ushort_t hb = f2bf(h_);
                    hh[nloc * HPAD + j] = hb;
                    xs_nxt[(nloc >> 1) * LPI + (nloc & 1) * H + j] = hb;
                }
            }
        }
        __syncthreads();   // hh ready
        if (w == 0) {
            frag_cd ha = (frag_cd){0.f, 0.f, 0.f, 0.f};
#pragma unroll
            for (int kc8 = 0; kc8 < 4; ++kc8) {
                frag_ab av = *(const frag_ab*)&hh[mA * HPAD + (kc8 * 4 + q) * 8];
                ha = __builtin_amdgcn_mfma_f32_16x16x32_bf16(av, wb[kc8], ha, 0, 0, 0);
            }
            if (nlane < NC) {
#pragma unroll
                for (int r = 0; r < 4; ++r) {
                    int nd = q * 4 + r;
                    if (nd < N) outp[(size_t)nd * NC + nlane] = ha[r] + bout_l;
                }
            }
        }
        outp += (size_t)N * NC;
    }
}

extern "C" void kernel_launch(void* const* d_in, const int* in_sizes, int n_in,
                              void* d_out, int out_size, void* d_ws, size_t ws_size,
                              hipStream_t stream)
{
    const int*   tokens = (const int*)d_in[0];
    const int*   labels = (const int*)d_in[1];
    const float* embed  = (const float*)d_in[2];
    const float* Wi = (const float*)d_in[3];  const float* bi  = (const float*)d_in[4];
    const float* Wo = (const float*)d_in[5];  const float* bo  = (const float*)d_in[6];
    const float* Wu = (const float*)d_in[7];  const float* bu  = (const float*)d_in[8];
    const float* Ui = (const float*)d_in[9];  const float* bui = (const float*)d_in[10];
    const float* Uo = (const float*)d_in[11]; const float* buo = (const float*)d_in[12];
    const float* Uu = (const float*)d_in[13]; const float* buu = (const float*)d_in[14];
    const float* F1 = (const float*)d_in[15]; const float* bf1 = (const float*)d_in[16];
    const float* F2 = (const float*)d_in[17]; const float* bf2 = (const float*)d_in[18];
    const float* Wout = (const float*)d_in[19]; const float* bout = (const float*)d_in[20];
    float* out = (float*)d_out;

    const int NL = 65536;
    char* base = (char*)d_ws;
    ushort_t* Wf    = (ushort_t*)(base);                 // 262144 B used (slot 327680)
    ushort_t* Wlf   = (ushort_t*)(base + 327680);        // 98304 B
    ushort_t* Woutf = (ushort_t*)(base + 425984);        // 4096 B
    ushort_t* hA    = (ushort_t*)(base + 430080);        // 16.8 MB
    ushort_t* hB    = (ushort_t*)(base + 17207296);      // 8.4 MB
    float*    cA    = (float*)   (base + 25595904);      // 33.6 MB
    float*    cB    = (float*)   (base + 59150336);      // 16.8 MB

    prep_weights<<<712, 256, 0, stream>>>(Ui, Uo, Uu, F1, F2, Wi, Wo, Wu, Wout,
                                          Wf, Wlf, Woutf);

    const size_t totalN = 2 * (size_t)NL - 1;            // 131071
    float* lab_out = out + totalN * NC;

    // leaf..l3 (65536+32768+16384+8192 nodes): only l3 h/c (8192 rows) -> hB/cB.
    leaf_l3_mfma<<<NL / 32, 512, 0, stream>>>(
        tokens, embed, Wlf, Wf, Woutf, bi, bo, bu, bui, buo, buu, bf1, bf2,
        bout, labels, lab_out, hB, cB, out);

    // l4..l7 (4096,2048,1024,512): reads l3 from hB/cB, writes l7 (512) -> hA/cA.
    subtree_mfma<<<128, 512, 0, stream>>>(
        hB, cB, Wf, Woutf, bui, buo, buu, bf1, bf2, bout, hA, cA,
        out + (size_t)122880 * NC);

    // l8..l11 (256,128,64,32): reads l7 from hA/cA, writes l11 (32) -> hB/cB.
    subtree_mfma<<<8, 512, 0, stream>>>(
        hA, cA, Wf, Woutf, bui, buo, buu, bf1, bf2, bout, hB, cB,
        out + (size_t)130560 * NC);

    // l12..l16 (16,8,4,2,1): reads l11 from hB/cB.
    tail_mfma<<<1, 512, 0, stream>>>(hB, cB, Wf, Woutf, bui, buo, buu, bf1, bf2,
                                     bout, out + (size_t)131040 * NC);
}

// Round 11
// 227.676 us; speedup vs baseline: 1.2715x; 1.2715x over previous
//
#include <hip/hip_runtime.h>
#include <hip/hip_bf16.h>
#include <math.h>

#define H    128
#define NC   5
#define LPI  264   // internal A row stride (ushorts): 256 + 8 pad
#define LPL  136   // leaf A row stride: 128 + 8 pad
#define HPAD 136   // head h row stride
#define CBP  132   // child-c LDS row stride (floats): 128 + 4 (breaks 4-way bank alias)

typedef unsigned short ushort_t;
using frag_ab = __attribute__((ext_vector_type(8))) short;   // 8 bf16 (4 VGPRs)
using frag_cd = __attribute__((ext_vector_type(4))) float;   // 4 fp32 acc

// Fast activations: plain a/b compiles to the correctly-rounded
// div_scale/div_fmas/div_fixup sequence (~10 VALU ops) without fast-math.
// v_rcp_f32 (~1 ulp) is 1 op; perturbation ~1e-7 << bf16 absmax ~1e-3.
__device__ __forceinline__ float fsig(float x) {
    return __builtin_amdgcn_rcpf(1.0f + __expf(-x));
}
__device__ __forceinline__ float ftanh_(float x) {
    float e = __expf(-2.0f * fabsf(x));
    float t = (1.0f - e) * __builtin_amdgcn_rcpf(1.0f + e);
    return copysignf(t, x);
}
__device__ __forceinline__ ushort_t f2bf(float f) {
    __hip_bfloat16 b = __float2bfloat16(f);
    return *reinterpret_cast<ushort_t*>(&b);
}

// ---------------------------------------------------------------------------
// Prep: B-fragment-native bf16 layouts.
//   Wf   [kcq][512 cols][8]  cols = [Ui|Uo|Uu|F], F panel: k<128 -> F1, k>=128 -> F2
//   Wlf  [kcq][384 cols][8]  cols = [Wi|Wo|Wu], K=128
//   Woutf[kcq][16  cols][8]  cols 0..4 = classes, rest 0, K=128
// ---------------------------------------------------------------------------
__global__ __launch_bounds__(256) void prep_weights(
    const float* __restrict__ Ui, const float* __restrict__ Uo, const float* __restrict__ Uu,
    const float* __restrict__ F1, const float* __restrict__ F2,
    const float* __restrict__ Wi, const float* __restrict__ Wo, const float* __restrict__ Wu,
    const float* __restrict__ Wout,
    ushort_t* __restrict__ Wf, ushort_t* __restrict__ Wlf, ushort_t* __restrict__ Woutf)
{
    int e = blockIdx.x * 256 + threadIdx.x;   // 712*256 = 182272 = 131072+49152+2048
    if (e < 131072) {
        int kc = e >> 12, rem = e & 4095;     // 512 cols * 8 = 4096 per kcq
        int n = rem >> 3, j7 = rem & 7;
        int k = kc * 8 + j7;
        int g = n >> 7, jc = n & 127;
        float v;
        if (g == 0)      v = Ui[jc * 256 + k];
        else if (g == 1) v = Uo[jc * 256 + k];
        else if (g == 2) v = Uu[jc * 256 + k];
        else             v = (k < 128) ? F1[jc * 128 + k] : F2[jc * 128 + k - 128];
        Wf[e] = f2bf(v);
    } else if (e < 180224) {
        int e2 = e - 131072;
        int kc = e2 / 3072, rem = e2 % 3072;
        int n = rem >> 3, j7 = rem & 7;
        int k = kc * 8 + j7;
        int g = n >> 7, jc = n & 127;
        float v = (g == 0) ? Wi[jc * 128 + k] : (g == 1) ? Wo[jc * 128 + k] : Wu[jc * 128 + k];
        Wlf[e2] = f2bf(v);
    } else {
        int e3 = e - 180224;               // 0..2047
        int kcq = e3 >> 7, rem = e3 & 127;
        int col = rem >> 3, j7 = rem & 7;
        int k = kcq * 8 + j7;
        float v = (col < NC) ? Wout[col * H + k] : 0.0f;
        Woutf[e3] = f2bf(v);
    }
}

// ---------------------------------------------------------------------------
// Fused leaf + level-1, 512 threads / 8 waves: one jt per wave. (R8: 63 us)
// l1 head uses its own hh2 buffer so the "leaf head done" barrier is gone:
// waves 2-7 enter l1 MFMAs while waves 0-1 finish the leaf head.
// ---------------------------------------------------------------------------
__global__ __launch_bounds__(512) void leaf_l1_mfma(
    const int* __restrict__ tokens, const float* __restrict__ embed,
    const ushort_t* __restrict__ Wlf, const ushort_t* __restrict__ Wf,
    const ushort_t* __restrict__ Woutf,
    const float* __restrict__ bi, const float* __restrict__ bo, const float* __restrict__ bu,
    const float* __restrict__ bui, const float* __restrict__ buo, const float* __restrict__ buu,
    const float* __restrict__ bf1, const float* __restrict__ bf2,
    const float* __restrict__ bout,
    const int* __restrict__ labels, float* __restrict__ lab_out,
    ushort_t* __restrict__ h1_out, float* __restrict__ c1_out,
    float* __restrict__ out_leaf, float* __restrict__ out_l1)
{
    __shared__ ushort_t xs [32 * LPL];    // leaf A rows (bf16 embed)
    __shared__ ushort_t hh [32 * HPAD];   // leaf head rows
    __shared__ ushort_t hh2[16 * HPAD];   // l1 head rows (separate: kills a barrier)
    __shared__ float    cbL[32 * CBP];    // leaf c
    __shared__ ushort_t xs2[16 * LPI];    // L1 A rows = [h_left | h_right]
    const int tid = threadIdx.x;
    const int node_base  = blockIdx.x * 32;   // leaf base
    const int node1_base = blockIdx.x * 16;   // L1 base

    // fused labels: 2048 blocks * 64 = 131072 >= 131071
    if (tid < 64) {
        int id = blockIdx.x * 64 + tid;
        if (id < 131071) lab_out[id] = (float)labels[id];
    }

    // stage leaf A: 512 threads, node m = tid>>4, 8 floats at kp=(tid&15)*8
    {
        int m = tid >> 4, kp = (tid & 15) * 8;
        const float* src = embed + (size_t)tokens[node_base + m] * H + kp;
        ushort_t tmp[8];
#pragma unroll
        for (int v = 0; v < 2; ++v) {
            float4 f = *(const float4*)(src + v * 4);
            tmp[v * 4 + 0] = f2bf(f.x); tmp[v * 4 + 1] = f2bf(f.y);
            tmp[v * 4 + 2] = f2bf(f.z); tmp[v * 4 + 3] = f2bf(f.w);
        }
        *(uint4*)&xs[m * LPL + kp] = *(uint4*)tmp;
    }

    const int w = tid >> 6, lane = tid & 63;
    const int mA = lane & 15, q = lane >> 4, nlane = lane & 15;

    frag_ab wb[4];
#pragma unroll
    for (int kc8 = 0; kc8 < 4; ++kc8)
        wb[kc8] = *(const frag_ab*)&Woutf[(((kc8 * 4 + q) * 16) + nlane) * 8];
    float bout_l = (nlane < NC) ? bout[nlane] : 0.0f;

    const int jt = w;                      // one j-tile per wave
    const int j = jt * 16 + nlane;
    __syncthreads();                       // xs ready

    // ---- leaf LSTM (K=128, gates i,o,u; this wave's jt only) ----
    frag_ab a[2][4];
#pragma unroll
    for (int t = 0; t < 2; ++t)
#pragma unroll
        for (int kc8 = 0; kc8 < 4; ++kc8)
            a[t][kc8] = *(const frag_ab*)&xs[(t * 16 + mA) * LPL + (kc8 * 4 + q) * 8];

    {
        frag_cd acc[3][2];
#pragma unroll
        for (int g = 0; g < 3; ++g)
#pragma unroll
            for (int t = 0; t < 2; ++t) acc[g][t] = (frag_cd){0.f, 0.f, 0.f, 0.f};
#pragma unroll
        for (int kc8 = 0; kc8 < 4; ++kc8) {
            int kcq = kc8 * 4 + q;
            const ushort_t* wp = &Wlf[((size_t)kcq * 384 + jt * 16 + nlane) * 8];
#pragma unroll
            for (int g = 0; g < 3; ++g) {
                frag_ab b = *(const frag_ab*)(wp + (size_t)g * H * 8);
                acc[g][0] = __builtin_amdgcn_mfma_f32_16x16x32_bf16(a[0][kc8], b, acc[g][0], 0, 0, 0);
                acc[g][1] = __builtin_amdgcn_mfma_f32_16x16x32_bf16(a[1][kc8], b, acc[g][1], 0, 0, 0);
            }
        }
        float bi_ = bi[j], bo_ = bo[j], bu_ = bu[j];
#pragma unroll
        for (int t = 0; t < 2; ++t)
#pragma unroll
            for (int r = 0; r < 4; ++r) {
                int nloc = t * 16 + q * 4 + r;
                float i_ = fsig(acc[0][t][r] + bi_);
                float o_ = fsig(acc[1][t][r] + bo_);
                float u_ = ftanh_(acc[2][t][r] + bu_);
                float c_ = i_ * u_;
                float h_ = o_ * ftanh_(c_);
                cbL[nloc * CBP + j] = c_;                 // leaf c stays in LDS
                ushort_t hb = f2bf(h_);
                hh[nloc * HPAD + j] = hb;                 // for leaf head
                xs2[(nloc >> 1) * LPI + (nloc & 1) * H + j] = hb;   // L1 A row
            }
    }
    __syncthreads();                       // hh/cbL/xs2 ready

    // ---- leaf head (waves 0,1) + L1 A-fragment loads; NO barrier after the
    //      head: l1 phase writes hh2/global only (hh stays stable) ----
    frag_ab a1[8];
#pragma unroll
    for (int kc8 = 0; kc8 < 8; ++kc8)
        a1[kc8] = *(const frag_ab*)&xs2[mA * LPI + (kc8 * 4 + q) * 8];

    if (w < 2) {
        frag_cd ha = (frag_cd){0.f, 0.f, 0.f, 0.f};
#pragma unroll
        for (int kc8 = 0; kc8 < 4; ++kc8) {
            frag_ab av = *(const frag_ab*)&hh[(w * 16 + mA) * HPAD + (kc8 * 4 + q) * 8];
            ha = __builtin_amdgcn_mfma_f32_16x16x32_bf16(av, wb[kc8], ha, 0, 0, 0);
        }
        if (nlane < NC) {
#pragma unroll
            for (int r = 0; r < 4; ++r)
                out_leaf[(size_t)(node_base + w * 16 + q * 4 + r) * NC + nlane] = ha[r] + bout_l;
        }
    }

    // ---- L1 LSTM (K=256, 4 fused panels; this wave's jt only) ----
    {
        frag_cd acc[5];
#pragma unroll
        for (int g = 0; g < 5; ++g) acc[g] = (frag_cd){0.f, 0.f, 0.f, 0.f};
#pragma unroll
        for (int kc8 = 0; kc8 < 8; ++kc8) {
            int kcq = kc8 * 4 + q;
            const ushort_t* wp = &Wf[((size_t)kcq * 512 + jt * 16 + nlane) * 8];
#pragma unroll
            for (int g = 0; g < 4; ++g) {
                frag_ab b = *(const frag_ab*)(wp + (size_t)g * H * 8);
                int gi = (g < 3) ? g : (kc8 < 4 ? 3 : 4);   // F panel: kc8<4 -> f1, else f2
                acc[gi] = __builtin_amdgcn_mfma_f32_16x16x32_bf16(a1[kc8], b, acc[gi], 0, 0, 0);
            }
        }
        float bi_ = bui[j], bo_ = buo[j], bu_ = buu[j], b1_ = bf1[j], b2_ = bf2[j];
#pragma unroll
        for (int r = 0; r < 4; ++r) {
            int nloc = q * 4 + r;
            int nd = node1_base + nloc;
            float i_  = fsig(acc[0][r] + bi_);
            float o_  = fsig(acc[1][r] + bo_);
            float u_  = ftanh_(acc[2][r] + bu_);
            float f1_ = fsig(acc[3][r] + b1_);
            float f2_ = fsig(acc[4][r] + b2_);
            float cl = cbL[(2 * nloc) * CBP + j];
            float cr = cbL[(2 * nloc + 1) * CBP + j];
            float c_ = fmaf(i_, u_, fmaf(f1_, cl, f2_ * cr));
            float h_ = o_ * ftanh_(c_);
            c1_out[(size_t)nd * H + j] = c_;
            ushort_t hb = f2bf(h_);
            h1_out[(size_t)nd * H + j] = hb;
            hh2[nloc * HPAD + j] = hb;
        }
    }
    __syncthreads();                       // L1 hh2 ready

    if (w == 0) {                          // L1 head: one 16-row tile
        frag_cd ha = (frag_cd){0.f, 0.f, 0.f, 0.f};
#pragma unroll
        for (int kc8 = 0; kc8 < 4; ++kc8) {
            frag_ab av = *(const frag_ab*)&hh2[mA * HPAD + (kc8 * 4 + q) * 8];
            ha = __builtin_amdgcn_mfma_f32_16x16x32_bf16(av, wb[kc8], ha, 0, 0, 0);
        }
        if (nlane < NC) {
#pragma unroll
            for (int r = 0; r < 4; ++r)
                out_l1[(size_t)(node1_base + q * 4 + r) * NC + nlane] = ha[r] + bout_l;
        }
    }
}

// ---------------------------------------------------------------------------
// Subtree kernel: FOUR levels per block (32 -> 16 -> 8 -> 4 nodes). Only the
// LAST level's h/c goes to global. 512 thr / 8 waves, one jt per wave.
// (R9-proven; R10 showed moving MORE levels into the leaf kernel loses.)
// ---------------------------------------------------------------------------
__global__ __launch_bounds__(512) void subtree_mfma(
    const ushort_t* __restrict__ h_prev, const float* __restrict__ c_prev,
    const ushort_t* __restrict__ Wf, const ushort_t* __restrict__ Woutf,
    const float* __restrict__ bui, const float* __restrict__ buo, const float* __restrict__ buu,
    const float* __restrict__ bf1, const float* __restrict__ bf2,
    const float* __restrict__ bout,
    ushort_t* __restrict__ h_out, float* __restrict__ c_out,
    float* __restrict__ out_base)
{
    __shared__ ushort_t xsA[32 * LPI];   // A rows, even levels
    __shared__ ushort_t xsB[16 * LPI];   // A rows, odd levels
    __shared__ float    cbA[32 * CBP];   // c, even-level outputs
    __shared__ float    cbB[16 * CBP];   // c, odd-level outputs
    __shared__ ushort_t hh [32 * HPAD];
    const int tid = threadIdx.x;
    const int NB  = gridDim.x;

    {   // stage level-0 A: 32 rows x 256 from h_prev (64 children x 128)
        int m = tid >> 4, kp = (tid & 15) * 16;
        const uint4* s = (const uint4*)(h_prev +
            ((size_t)2 * (blockIdx.x * 32 + m) + (kp >> 7)) * H + (kp & 127));
        uint4* d = (uint4*)&xsA[m * LPI + kp];
        d[0] = s[0]; d[1] = s[1];
    }

    const int w = tid >> 6, lane = tid & 63;
    const int mA = lane & 15, q = lane >> 4, nlane = lane & 15;

    frag_ab wb[4];
#pragma unroll
    for (int kc8 = 0; kc8 < 4; ++kc8)
        wb[kc8] = *(const frag_ab*)&Woutf[(((kc8 * 4 + q) * 16) + nlane) * 8];
    float bout_l = (nlane < NC) ? bout[nlane] : 0.0f;

    const int jt = w;                    // one j-tile per wave
    const int j = jt * 16 + nlane;
    const float bi_ = bui[j], bo_ = buo[j], bu_ = buu[j], b1_ = bf1[j], b2_ = bf2[j];

    size_t out_off = 0;
    for (int lev = 0; lev < 4; ++lev) {
        const int N = 32 >> lev;                       // nodes/block this level
        const int ntiles = (N + 15) >> 4;              // 2,1,1,1
        const int gbase = blockIdx.x * N;              // global node base
        ushort_t* xs_cur = (lev & 1) ? xsB : xsA;
        ushort_t* xs_nxt = (lev & 1) ? xsA : xsB;
        float*    cb_out = (lev & 1) ? cbB : cbA;
        const float* cb_in = (lev & 1) ? cbA : cbB;
        __syncthreads();   // A/c ready; previous head done

        for (int t = 0; t < ntiles; ++t) {
            frag_cd acc[5];
#pragma unroll
            for (int g = 0; g < 5; ++g) acc[g] = (frag_cd){0.f, 0.f, 0.f, 0.f};
#pragma unroll
            for (int kc8 = 0; kc8 < 8; ++kc8) {
                int kcq = kc8 * 4 + q;
                frag_ab av = *(const frag_ab*)&xs_cur[(t * 16 + mA) * LPI + kcq * 8];
                const ushort_t* wp = &Wf[((size_t)kcq * 512 + jt * 16 + nlane) * 8];
#pragma unroll
                for (int g = 0; g < 4; ++g) {
                    frag_ab b = *(const frag_ab*)(wp + (size_t)g * H * 8);
                    int gi = (g < 3) ? g : (kc8 < 4 ? 3 : 4);   // constant after unroll
                    acc[gi] = __builtin_amdgcn_mfma_f32_16x16x32_bf16(av, b, acc[gi], 0, 0, 0);
                }
            }
#pragma unroll
            for (int r = 0; r < 4; ++r) {
                int nloc = t * 16 + q * 4 + r;
                if (nloc < N) {
                    float i_  = fsig(acc[0][r] + bi_);
                    float o_  = fsig(acc[1][r] + bo_);
                    float u_  = ftanh_(acc[2][r] + bu_);
                    float f1_ = fsig(acc[3][r] + b1_);
                    float f2_ = fsig(acc[4][r] + b2_);
                    float cl, cr;
                    if (lev == 0) {
                        cl = c_prev[((size_t)2 * (gbase + nloc)) * H + j];
                        cr = c_prev[((size_t)2 * (gbase + nloc) + 1) * H + j];
                    } else {
                        cl = cb_in[(2 * nloc) * CBP + j];
                        cr = cb_in[(2 * nloc + 1) * CBP + j];
                    }
                    float c_ = fmaf(i_, u_, fmaf(f1_, cl, f2_ * cr));
                    float h_ = o_ * ftanh_(c_);
                    ushort_t hb = f2bf(h_);
                    hh[nloc * HPAD + j] = hb;
                    if (lev < 3) {
                        cb_out[nloc * CBP + j] = c_;
                        xs_nxt[(nloc >> 1) * LPI + (nloc & 1) * H + j] = hb;
                    } else {            // last level: h/c to global for next dispatch
                        c_out[(size_t)(gbase + nloc) * H + j] = c_;
                        h_out[(size_t)(gbase + nloc) * H + j] = hb;
                    }
                }
            }
        }
        __syncthreads();   // hh ready
        if (w < ntiles) {
            frag_cd ha = (frag_cd){0.f, 0.f, 0.f, 0.f};
#pragma unroll
            for (int kc8 = 0; kc8 < 4; ++kc8) {
                frag_ab av = *(const frag_ab*)&hh[(w * 16 + mA) * HPAD + (kc8 * 4 + q) * 8];
                ha = __builtin_amdgcn_mfma_f32_16x16x32_bf16(av, wb[kc8], ha, 0, 0, 0);
            }
            if (nlane < NC) {
#pragma unroll
                for (int r = 0; r < 4; ++r) {
                    int nd = w * 16 + q * 4 + r;
                    if (nd < N)
                        out_base[out_off + (size_t)(gbase + nd) * NC + nlane] = ha[r] + bout_l;
                }
            }
        }
        out_off += (size_t)NB * N * NC;
    }
}

// ---------------------------------------------------------------------------
// Tail: levels N=64,32,16,8,4,2,1 in ONE block of 512 threads (8 waves).
// ---------------------------------------------------------------------------
__global__ __launch_bounds__(512) void tail_mfma(
    const ushort_t* __restrict__ h_prev, const float* __restrict__ c_prev,
    const ushort_t* __restrict__ Wf, const ushort_t* __restrict__ Woutf,
    const float* __restrict__ bui, const float* __restrict__ buo, const float* __restrict__ buu,
    const float* __restrict__ bf1, const float* __restrict__ bf2,
    const float* __restrict__ bout, float* __restrict__ out)
{
    __shared__ ushort_t xsA[64 * LPI];   // A rows, even levels
    __shared__ ushort_t xsB[32 * LPI];   // A rows, odd levels
    __shared__ float    cbA[64 * H];
    __shared__ float    cbB[32 * H];
    __shared__ ushort_t hh[64 * HPAD];
    const int tid = threadIdx.x;
    const int w = tid >> 6, lane = tid & 63;
    const int mA = lane & 15, q = lane >> 4, nlane = lane & 15;

    {   // stage level-0 A: 64 rows x 256 from h_prev (128 children x 128)
        int m = tid >> 3, kp = (tid & 7) * 32;
        const uint4* s = (const uint4*)(h_prev + ((size_t)2 * m + (kp >> 7)) * H + (kp & 127));
        uint4* d = (uint4*)&xsA[m * LPI + kp];
#pragma unroll
        for (int i = 0; i < 4; ++i) d[i] = s[i];
    }

    frag_ab wb[4];
#pragma unroll
    for (int kc8 = 0; kc8 < 4; ++kc8)
        wb[kc8] = *(const frag_ab*)&Woutf[(((kc8 * 4 + q) * 16) + nlane) * 8];
    float bout_l = (nlane < NC) ? bout[nlane] : 0.0f;

    const int jt = w;                    // one j-tile per wave
    const int j = jt * 16 + nlane;
    const float bi_ = bui[j], bo_ = buo[j], bu_ = buu[j], b1_ = bf1[j], b2_ = bf2[j];

    float* outp = out;
    for (int lev = 0; lev < 7; ++lev) {
        const int N = 64 >> lev;
        const int ntiles = (N + 15) >> 4;
        ushort_t* xs_cur = (lev & 1) ? xsB : xsA;
        ushort_t* xs_nxt = (lev & 1) ? xsA : xsB;
        float*    cb_out = (lev & 1) ? cbB : cbA;
        const float* cb_in = (lev & 1) ? cbA : cbB;
        __syncthreads();   // A/c ready; previous head done

        for (int t = 0; t < ntiles; ++t) {
            frag_cd acc[5];
#pragma unroll
            for (int g = 0; g < 5; ++g) acc[g] = (frag_cd){0.f, 0.f, 0.f, 0.f};
#pragma unroll
            for (int kc8 = 0; kc8 < 8; ++kc8) {
                int kcq = kc8 * 4 + q;
                frag_ab av = *(const frag_ab*)&xs_cur[(t * 16 + mA) * LPI + kcq * 8];
                const ushort_t* wp = &Wf[((size_t)kcq * 512 + jt * 16 + nlane) * 8];
#pragma unroll
                for (int g = 0; g < 4; ++g) {
                    frag_ab b = *(const frag_ab*)(wp + (size_t)g * H * 8);
                    int gi = (g < 3) ? g : (kc8 < 4 ? 3 : 4);   // constant after unroll
                    acc[gi] = __builtin_amdgcn_mfma_f32_16x16x32_bf16(av, b, acc[gi], 0, 0, 0);
                }
            }
#pragma unroll
            for (int r = 0; r < 4; ++r) {
                int nloc = t * 16 + q * 4 + r;
                if (nloc < N) {
                    float i_  = fsig(acc[0][r] + bi_);
                    float o_  = fsig(acc[1][r] + bo_);
                    float u_  = ftanh_(acc[2][r] + bu_);
                    float f1_ = fsig(acc[3][r] + b1_);
                    float f2_ = fsig(acc[4][r] + b2_);
                    float cl, cr;
                    if (lev == 0) {
                        cl = c_prev[((size_t)2 * nloc) * H + j];
                        cr = c_prev[((size_t)2 * nloc + 1) * H + j];
                    } else {
                        cl = cb_in[(2 * nloc) * H + j];
                        cr = cb_in[(2 * nloc + 1) * H + j];
                    }
                    float c_ = fmaf(i_, u_, fmaf(f1_, cl, f2_ * cr));
                    float h_ = o_ * ftanh_(c_);
                    cb_out[nloc * H + j] = c_;
                    ushort_t hb = f2bf(h_);
                    hh[nloc * HPAD + j] = hb;
                    xs_nxt[(nloc >> 1) * LPI + (nloc & 1) * H + j] = hb;
                }
            }
        }
        __syncthreads();   // hh ready
        if (w < ntiles) {
            frag_cd ha = (frag_cd){0.f, 0.f, 0.f, 0.f};
#pragma unroll
            for (int kc8 = 0; kc8 < 4; ++kc8) {
                frag_ab av = *(const frag_ab*)&hh[(w * 16 + mA) * HPAD + (kc8 * 4 + q) * 8];
                ha = __builtin_amdgcn_mfma_f32_16x16x32_bf16(av, wb[kc8], ha, 0, 0, 0);
            }
            if (nlane < NC) {
#pragma unroll
                for (int r = 0; r < 4; ++r) {
                    int nd = w * 16 + q * 4 + r;
                    if (nd < N) outp[(size_t)nd * NC + nlane] = ha[r] + bout_l;
                }
            }
        }
        outp += (size_t)N * NC;
    }
}

extern "C" void kernel_launch(void* const* d_in, const int* in_sizes, int n_in,
                              void* d_out, int out_size, void* d_ws, size_t ws_size,
                              hipStream_t stream)
{
    const int*   tokens = (const int*)d_in[0];
    const int*   labels = (const int*)d_in[1];
    const float* embed  = (const float*)d_in[2];
    const float* Wi = (const float*)d_in[3];  const float* bi  = (const float*)d_in[4];
    const float* Wo = (const float*)d_in[5];  const float* bo  = (const float*)d_in[6];
    const float* Wu = (const float*)d_in[7];  const float* bu  = (const float*)d_in[8];
    const float* Ui = (const float*)d_in[9];  const float* bui = (const float*)d_in[10];
    const float* Uo = (const float*)d_in[11]; const float* buo = (const float*)d_in[12];
    const float* Uu = (const float*)d_in[13]; const float* buu = (const float*)d_in[14];
    const float* F1 = (const float*)d_in[15]; const float* bf1 = (const float*)d_in[16];
    const float* F2 = (const float*)d_in[17]; const float* bf2 = (const float*)d_in[18];
    const float* Wout = (const float*)d_in[19]; const float* bout = (const float*)d_in[20];
    float* out = (float*)d_out;

    const int NL = 65536;
    char* base = (char*)d_ws;
    ushort_t* Wf    = (ushort_t*)(base);                 // 262144 B used (slot 327680)
    ushort_t* Wlf   = (ushort_t*)(base + 327680);        // 98304 B
    ushort_t* Woutf = (ushort_t*)(base + 425984);        // 4096 B
    ushort_t* hA    = (ushort_t*)(base + 430080);        // 16.8 MB
    ushort_t* hB    = (ushort_t*)(base + 17207296);      // 8.4 MB
    float*    cA    = (float*)   (base + 25595904);      // 33.6 MB
    float*    cB    = (float*)   (base + 59150336);      // 16.8 MB

    prep_weights<<<712, 256, 0, stream>>>(Ui, Uo, Uu, F1, F2, Wi, Wo, Wu, Wout,
                                          Wf, Wlf, Woutf);

    const size_t totalN = 2 * (size_t)NL - 1;            // 131071
    float* lab_out = out + totalN * NC;

    // leaf + l1 (32768 nodes): h/c of l1 -> hB/cB.
    leaf_l1_mfma<<<NL / 32, 512, 0, stream>>>(
        tokens, embed, Wlf, Wf, Woutf, bi, bo, bu, bui, buo, buu, bf1, bf2,
        bout, labels, lab_out, hB, cB, out, out + (size_t)NL * NC);

    size_t off = (size_t)(NL + NL / 2) * NC;             // after leaf + l1 outputs

    // subtree0: levels l2..l5 (16384,8192,4096,2048). Only l5 h/c -> hA/cA.
    subtree_mfma<<<512, 512, 0, stream>>>(
        hB, cB, Wf, Woutf, bui, buo, buu, bf1, bf2, bout, hA, cA, out + off);
    off += (size_t)(16384 + 8192 + 4096 + 2048) * NC;

    // subtree1: levels l6..l9 (1024,512,256,128). Only l9 h/c -> hB/cB.
    subtree_mfma<<<32, 512, 0, stream>>>(
        hA, cA, Wf, Woutf, bui, buo, buu, bf1, bf2, bout, hB, cB, out + off);
    off += (size_t)(1024 + 512 + 256 + 128) * NC;

    // tail: levels l10..l16 (64..1) from hB/cB.
    tail_mfma<<<1, 512, 0, stream>>>(hB, cB, Wf, Woutf, bui, buo, buu, bf1, bf2,
                                     bout, out + off);
}